// Round 4
// baseline (39.618 us; speedup 1.0000x reference)
//
#include <hip/hip_runtime.h>
#include <utility>
#include <cmath>

// Problem constants (fixed by the reference setup)
constexpr int T = 2048;
constexpr int B = 8;
constexpr int C = 1024;
constexpr int H = 16;
constexpr int K = 31;
constexpr int PAD = 15;               // PADDING_L
constexpr int NBC = B * C;            // 8192 = t-stride in elements; (b,c) contiguous
constexpr int BC_TILE = 64;           // columns per block == R (one head per block)
constexpr int T_TILE = 64;            // t-outputs per tile
constexpr int ROWS = T_TILE + K - 1;  // 94 rows needed (incl. halo)
constexpr int ROWS4 = 96;             // staged rows, multiple of 4 (x4-wide staging)
constexpr int BLOCK = 256;            // 4 waves
constexpr int WAVES = BLOCK / 64;
constexpr int TT = T_TILE / WAVES;    // 16 t-outputs per thread
constexpr int WIN = TT + K - 1;       // 46 register window
constexpr int TPB = 4;                // t-tiles per block (pipelined)
constexpr int NCHUNK = (T / T_TILE) / TPB;          // 8
constexpr int GPW = ROWS4 / 4 / WAVES;              // 6 gld_lds instrs per wave per tile
static_assert(GPW == 6, "vmcnt literal below assumes 6");

__device__ __forceinline__ float uniform_f(float v) {
    return __int_as_float(__builtin_amdgcn_readfirstlane(__float_as_int(v)));
}

// async global->LDS, 16 bytes/lane: LDS dest = base + lane*16 (4 rows of 64 floats
// per instruction); global source is per-lane.
__device__ __forceinline__ void gld_lds_b128(const float* gsrc, float* ldst) {
    __builtin_amdgcn_global_load_lds(
        (const __attribute__((address_space(1))) unsigned int*)gsrc,
        (__attribute__((address_space(3))) unsigned int*)ldst,
        16, 0, 0);
}

// One tap: KK compile-time -> w[KK] in SGPR, xv[i+KK] statically-indexed register.
template <int KK>
__device__ __forceinline__ void tap(float (&acc)[TT], const float (&xv)[WIN], float wk) {
#pragma unroll
    for (int i = 0; i < TT; ++i)
        acc[i] = fmaf(wk, xv[i + KK], acc[i]);
}

template <int... Ks>
__device__ __forceinline__ void all_taps(float (&acc)[TT], const float (&xv)[WIN],
                                         const float (&w)[K],
                                         std::integer_sequence<int, Ks...>) {
    (tap<Ks>(acc, xv, w[Ks]), ...);
}

__global__ __launch_bounds__(BLOCK, 1) void lconv_tbc_kernel(
    const float* __restrict__ x,      // (T, B, C)
    const float* __restrict__ wgt,    // (H, 1, K)
    const float* __restrict__ bias,   // (C)
    const float* __restrict__ zbuf,   // 256B of zeros (d_ws)
    float* __restrict__ out)          // (T, B, C)
{
    __shared__ float xs[2][ROWS4 * BC_TILE];   // 2 x 24576 B
    __shared__ float sw[K];

    const int tid  = threadIdx.x;
    const int wave = tid >> 6;
    const int lane = tid & 63;
    const int bc0  = blockIdx.x * BC_TILE;               // head-aligned
    const int tchunk0 = blockIdx.y * (TPB * T_TILE);     // this block's t range

    const int lane_row = lane >> 4;          // 0..3  (row within 4-row group)
    const int lane_col = (lane & 15) * 4;    // float col within row
    const ptrdiff_t lane_off = (ptrdiff_t)lane_row * NBC + lane_col;
    const float* zsrc = zbuf + lane_col;     // 16B-aligned zero source

    // stage one tile (ROWS4 rows) into xs[buf]; 6 gld_lds per wave
    auto stage_tile = [&](int buf, int ttile) {
        const int tst = ttile - PAD;
        float* ldsb = &xs[buf][(wave * GPW) * 4 * BC_TILE];
        #pragma unroll
        for (int s = 0; s < GPW; ++s) {
            const int g   = wave * GPW + s;
            const int tg0 = tst + 4 * g;
            const int tg  = tg0 + lane_row;                  // per-lane global row
            const float* src = x + (ptrdiff_t)tg0 * NBC + bc0 + lane_off;
            const float* p   = ((unsigned)tg < (unsigned)T) ? src : zsrc;
            gld_lds_b128(p, ldsb + s * 4 * BC_TILE);
        }
    };

    // ---- prologue: kick off tile 0, softmax taps meanwhile ----
    stage_tile(0, tchunk0);

    if (wave == 0) {
        const int head = (bc0 & (C - 1)) >> 6;   // 64 channels share a head
        float raw = (lane < K) ? wgt[head * K + lane] : -INFINITY;
        float m = raw;
        #pragma unroll
        for (int off = 32; off >= 1; off >>= 1) m = fmaxf(m, __shfl_xor(m, off));
        float e = (lane < K) ? expf(raw - m) : 0.0f;
        float s = e;
        #pragma unroll
        for (int off = 32; off >= 1; off >>= 1) s += __shfl_xor(s, off);
        if (lane < K) sw[lane] = e / s;
    }

    __syncthreads();   // full drain (tile0 + sw) — once per block only

    float w[K];
    #pragma unroll
    for (int k = 0; k < K; ++k) w[k] = uniform_f(sw[k]);
    const float bb = bias[(bc0 + lane) & (C - 1)];

    // ---- pipelined tile loop: stage(i+1) || compute(i) ----
    #pragma unroll 1
    for (int it = 0; it < TPB; ++it) {
        const int cur = it & 1;
        if (it + 1 < TPB) {
            stage_tile(cur ^ 1, tchunk0 + (it + 1) * T_TILE);
            // wait for tile `it` only; the 6 just-issued loads stay in flight
            asm volatile("s_waitcnt vmcnt(6)" ::: "memory");
        } else {
            asm volatile("s_waitcnt vmcnt(0)" ::: "memory");
        }
        __builtin_amdgcn_s_barrier();

        // 46 statically-indexed LDS reads (stride 256B, conflict-free)
        float xv[WIN];
        const float* xrow = &xs[cur][(wave * TT) * BC_TILE + lane];
        #pragma unroll
        for (int j = 0; j < WIN; ++j)
            xv[j] = xrow[j * BC_TILE];

        float acc[TT];
        #pragma unroll
        for (int i = 0; i < TT; ++i) acc[i] = 0.0f;

        all_taps(acc, xv, w, std::make_integer_sequence<int, K>{});   // 31x16 static FMAs

        float* op = out + (size_t)(tchunk0 + it * T_TILE + wave * TT) * NBC + bc0 + lane;
        #pragma unroll
        for (int i = 0; i < TT; ++i)
            op[(size_t)i * NBC] = acc[i] + bb;

        // all waves done reading xs[cur] before it gets restaged next iteration
        __builtin_amdgcn_s_barrier();
    }
}

extern "C" void kernel_launch(void* const* d_in, const int* in_sizes, int n_in,
                              void* d_out, int out_size, void* d_ws, size_t ws_size,
                              hipStream_t stream) {
    const float* x    = (const float*)d_in[0];
    const float* wgt  = (const float*)d_in[1];
    const float* bias = (const float*)d_in[2];
    float* out        = (float*)d_out;
    float* zbuf       = (float*)d_ws;

    hipMemsetAsync(zbuf, 0, 256, stream);   // zero source for halo rows

    dim3 grid(NBC / BC_TILE, NCHUNK);       // (128, 8) = 1024 blocks
    lconv_tbc_kernel<<<grid, dim3(BLOCK), 0, stream>>>(x, wgt, bias, zbuf, out);
}

// Round 5
// 32.400 us; speedup vs baseline: 1.2228x; 1.2228x over previous
//
#include <hip/hip_runtime.h>
#include <utility>
#include <cmath>

// Problem constants (fixed by the reference setup)
constexpr int T = 2048;
constexpr int B = 8;
constexpr int C = 1024;
constexpr int H = 16;
constexpr int K = 31;
constexpr int PAD = 15;            // PADDING_L
constexpr int NBC = B * C;         // 8192 = t-stride in elements; (b,c) contiguous
constexpr int BLOCK = 256;         // 4 waves; each wave spans 64 bc -> one head
constexpr int TT = 16;             // t-outputs per thread
constexpr int WIN = TT + K - 1;    // 46-row register window

// One tap: KK compile-time -> w[KK] stays in SGPR, xv[i+KK] statically-indexed reg.
template <int KK>
__device__ __forceinline__ void tap(float (&acc)[TT], const float (&xv)[WIN], float wk) {
#pragma unroll
    for (int i = 0; i < TT; ++i)
        acc[i] = fmaf(wk, xv[i + KK], acc[i]);
}

template <int... Ks>
__device__ __forceinline__ void all_taps(float (&acc)[TT], const float (&xv)[WIN],
                                         const float (&w)[K],
                                         std::integer_sequence<int, Ks...>) {
    (tap<Ks>(acc, xv, w[Ks]), ...);
}

// Broadcast tap k from lane k to all lanes as a wave-uniform (SGPR) value,
// with compile-time lane indices (v_readlane_b32 with literal lane).
template <int... Ks>
__device__ __forceinline__ void bcast_taps(float (&w)[K], float v,
                                           std::integer_sequence<int, Ks...>) {
    ((w[Ks] = __int_as_float(__builtin_amdgcn_readlane(__float_as_int(v), Ks))), ...);
}

__global__ __launch_bounds__(BLOCK, 4) void lconv_tbc_kernel(
    const float* __restrict__ x,      // (T, B, C)
    const float* __restrict__ wgt,    // (H, 1, K)
    const float* __restrict__ bias,   // (C)
    float* __restrict__ out)          // (T, B, C)
{
    const int tid  = threadIdx.x;
    const int lane = tid & 63;
    const int bc   = blockIdx.x * BLOCK + tid;   // contiguous per wave
    const int c    = bc & (C - 1);
    const int t0   = blockIdx.y * TT;
    const int tstart = t0 - PAD;

    // ---- per-wave softmax of this wave's head (64 bc columns == one head) ----
    const int head = c >> 6;                     // wave-uniform
    float raw = (lane < K) ? wgt[head * K + lane] : -INFINITY;
    float m = raw;
    #pragma unroll
    for (int off = 32; off >= 1; off >>= 1) m = fmaxf(m, __shfl_xor(m, off));
    float e = (lane < K) ? expf(raw - m) : 0.0f;
    float s = e;
    #pragma unroll
    for (int off = 32; off >= 1; off >>= 1) s += __shfl_xor(s, off);
    const float myw = e / s;                     // lanes >= K hold 0

    float w[K];
    bcast_taps(w, myw, std::make_integer_sequence<int, K>{});   // 31x v_readlane -> SGPRs

    // ---- 46 independent coalesced loads into a statically-indexed register window ----
    float xv[WIN];
    if (tstart >= 0 && tstart + WIN <= T) {
        const float* xp = x + (size_t)tstart * NBC + bc;
        #pragma unroll
        for (int j = 0; j < WIN; ++j)
            xv[j] = xp[(size_t)j * NBC];
    } else {
        #pragma unroll
        for (int j = 0; j < WIN; ++j) {
            const int tg = tstart + j;
            xv[j] = ((unsigned)tg < (unsigned)T) ? x[(size_t)tg * NBC + bc] : 0.0f;
        }
    }

    // ---- 31 x 16 FMAs, every index compile-time ----
    float acc[TT];
    #pragma unroll
    for (int i = 0; i < TT; ++i) acc[i] = 0.0f;
    all_taps(acc, xv, w, std::make_integer_sequence<int, K>{});

    // ---- epilogue: bias + coalesced 256B/wave stores ----
    const float bb = bias[c];
    float* op = out + (size_t)t0 * NBC + bc;
    #pragma unroll
    for (int i = 0; i < TT; ++i)
        op[(size_t)i * NBC] = acc[i] + bb;
}

extern "C" void kernel_launch(void* const* d_in, const int* in_sizes, int n_in,
                              void* d_out, int out_size, void* d_ws, size_t ws_size,
                              hipStream_t stream) {
    const float* x    = (const float*)d_in[0];
    const float* wgt  = (const float*)d_in[1];
    const float* bias = (const float*)d_in[2];
    float* out        = (float*)d_out;

    dim3 grid(NBC / BLOCK, T / TT);   // (32, 128) = 4096 blocks, no barriers anywhere
    lconv_tbc_kernel<<<grid, dim3(BLOCK), 0, stream>>>(x, wgt, bias, out);
}

// Round 6
// 31.775 us; speedup vs baseline: 1.2468x; 1.0197x over previous
//
#include <hip/hip_runtime.h>
#include <utility>
#include <cmath>

// Problem constants (fixed by the reference setup)
constexpr int T = 2048;
constexpr int B = 8;
constexpr int C = 1024;
constexpr int H = 16;
constexpr int K = 31;
constexpr int PAD = 15;            // PADDING_L
constexpr int NBC = B * C;         // 8192 = t-stride in elements; (b,c) contiguous
constexpr int BLOCK = 256;         // 4 waves; each wave spans 64 bc -> one head
constexpr int TT = 32;             // t-outputs per thread
constexpr int WIN = TT + K - 1;    // 62-row register window (statically indexed)

// One tap: KK compile-time -> w[KK] stays in SGPR, xv[i+KK] statically-indexed reg.
template <int KK>
__device__ __forceinline__ void tap(float (&acc)[TT], const float (&xv)[WIN], float wk) {
#pragma unroll
    for (int i = 0; i < TT; ++i)
        acc[i] = fmaf(wk, xv[i + KK], acc[i]);
}

template <int... Ks>
__device__ __forceinline__ void all_taps(float (&acc)[TT], const float (&xv)[WIN],
                                         const float (&w)[K],
                                         std::integer_sequence<int, Ks...>) {
    (tap<Ks>(acc, xv, w[Ks]), ...);
}

// Broadcast tap k from lane k to all lanes as wave-uniform (SGPR) values,
// with compile-time lane indices (v_readlane_b32 with literal lane).
template <int... Ks>
__device__ __forceinline__ void bcast_taps(float (&w)[K], float v,
                                           std::integer_sequence<int, Ks...>) {
    ((w[Ks] = __int_as_float(__builtin_amdgcn_readlane(__float_as_int(v), Ks))), ...);
}

__global__ __launch_bounds__(BLOCK, 4) void lconv_tbc_kernel(
    const float* __restrict__ x,      // (T, B, C)
    const float* __restrict__ wgt,    // (H, 1, K)
    const float* __restrict__ bias,   // (C)
    float* __restrict__ out)          // (T, B, C)
{
    const int tid  = threadIdx.x;
    const int lane = tid & 63;
    const int bc   = blockIdx.x * BLOCK + tid;   // contiguous per wave
    const int c    = bc & (C - 1);
    const int t0   = blockIdx.y * TT;
    const int tstart = t0 - PAD;

    // ---- per-wave softmax of this wave's head (64 bc columns == one head) ----
    const int head = c >> 6;                     // wave-uniform
    float raw = (lane < K) ? wgt[head * K + lane] : -INFINITY;
    float m = raw;
    #pragma unroll
    for (int off = 32; off >= 1; off >>= 1) m = fmaxf(m, __shfl_xor(m, off));
    float e = (lane < K) ? expf(raw - m) : 0.0f;
    float s = e;
    #pragma unroll
    for (int off = 32; off >= 1; off >>= 1) s += __shfl_xor(s, off);
    const float myw = e / s;                     // lanes >= K hold 0

    float w[K];
    bcast_taps(w, myw, std::make_integer_sequence<int, K>{});   // 31x v_readlane -> SGPRs

    // ---- 62 independent coalesced loads into a statically-indexed register window ----
    float xv[WIN];
    if (tstart >= 0 && tstart + WIN <= T) {
        const float* xp = x + (size_t)tstart * NBC + bc;
        #pragma unroll
        for (int j = 0; j < WIN; ++j)
            xv[j] = xp[(size_t)j * NBC];
    } else {
        #pragma unroll
        for (int j = 0; j < WIN; ++j) {
            const int tg = tstart + j;
            xv[j] = ((unsigned)tg < (unsigned)T) ? x[(size_t)tg * NBC + bc] : 0.0f;
        }
    }

    // ---- 31 x 32 FMAs, every index compile-time ----
    float acc[TT];
    #pragma unroll
    for (int i = 0; i < TT; ++i) acc[i] = 0.0f;
    all_taps(acc, xv, w, std::make_integer_sequence<int, K>{});

    // ---- epilogue: bias + coalesced nontemporal stores (don't pollute L2) ----
    const float bb = bias[c];
    float* op = out + (size_t)t0 * NBC + bc;
    #pragma unroll
    for (int i = 0; i < TT; ++i)
        __builtin_nontemporal_store(acc[i] + bb, &op[(size_t)i * NBC]);
}

extern "C" void kernel_launch(void* const* d_in, const int* in_sizes, int n_in,
                              void* d_out, int out_size, void* d_ws, size_t ws_size,
                              hipStream_t stream) {
    const float* x    = (const float*)d_in[0];
    const float* wgt  = (const float*)d_in[1];
    const float* bias = (const float*)d_in[2];
    float* out        = (float*)d_out;

    dim3 grid(NBC / BLOCK, T / TT);   // (32, 64) = 2048 blocks, no barriers anywhere
    lconv_tbc_kernel<<<grid, dim3(BLOCK), 0, stream>>>(x, wgt, bias, out);
}

// Round 7
// 31.667 us; speedup vs baseline: 1.2511x; 1.0034x over previous
//
#include <hip/hip_runtime.h>
#include <utility>
#include <cmath>

// Problem constants (fixed by the reference setup)
constexpr int T = 2048;
constexpr int B = 8;
constexpr int C = 1024;
constexpr int H = 16;
constexpr int K = 31;
constexpr int PAD = 15;            // PADDING_L
constexpr int NBC = B * C;         // 8192 = t-stride in elements; (b,c) contiguous
constexpr int BLOCK = 256;         // 4 waves; each wave spans 64 bc -> one head
constexpr int TT = 32;             // t-outputs per thread
constexpr int WIN = TT + K - 1;    // 62-row register window (statically indexed)

// One tap: KK compile-time -> w[KK] stays in SGPR, xv[i+KK] statically-indexed reg.
template <int KK>
__device__ __forceinline__ void tap(float (&acc)[TT], const float (&xv)[WIN], float wk) {
#pragma unroll
    for (int i = 0; i < TT; ++i)
        acc[i] = fmaf(wk, xv[i + KK], acc[i]);
}

template <int... Ks>
__device__ __forceinline__ void all_taps(float (&acc)[TT], const float (&xv)[WIN],
                                         const float (&w)[K],
                                         std::integer_sequence<int, Ks...>) {
    (tap<Ks>(acc, xv, w[Ks]), ...);
}

// Broadcast tap k from lane k to all lanes as wave-uniform (SGPR) values,
// with compile-time lane indices (v_readlane_b32 with literal lane).
template <int... Ks>
__device__ __forceinline__ void bcast_taps(float (&w)[K], float v,
                                           std::integer_sequence<int, Ks...>) {
    ((w[Ks] = __int_as_float(__builtin_amdgcn_readlane(__float_as_int(v), Ks))), ...);
}

__global__ __launch_bounds__(BLOCK, 4) void lconv_tbc_kernel(
    const float* __restrict__ x,      // (T, B, C)
    const float* __restrict__ wgt,    // (H, 1, K)
    const float* __restrict__ bias,   // (C)
    float* __restrict__ out)          // (T, B, C)
{
    const int tid  = threadIdx.x;
    const int lane = tid & 63;
    const int bc   = blockIdx.x * BLOCK + tid;   // contiguous per wave
    const int c    = bc & (C - 1);
    const int t0   = blockIdx.y * TT;
    const int tstart = t0 - PAD;

    // ---- per-wave softmax of this wave's head (64 bc columns == one head) ----
    const int head = c >> 6;                     // wave-uniform
    float raw = (lane < K) ? wgt[head * K + lane] : -INFINITY;
    float m = raw;
    #pragma unroll
    for (int off = 32; off >= 1; off >>= 1) m = fmaxf(m, __shfl_xor(m, off));
    float e = (lane < K) ? expf(raw - m) : 0.0f;
    float s = e;
    #pragma unroll
    for (int off = 32; off >= 1; off >>= 1) s += __shfl_xor(s, off);
    const float myw = e / s;                     // lanes >= K hold 0

    float w[K];
    bcast_taps(w, myw, std::make_integer_sequence<int, K>{});   // 31x v_readlane -> SGPRs

    // ---- 62 independent coalesced loads into a statically-indexed register window.
    // Wave-uniform row pointer + per-lane bc index -> saddr-form loads.
    float xv[WIN];
    if (tstart >= 0 && tstart + WIN <= T) {
        const float* rowp = x + (size_t)tstart * NBC;
        #pragma unroll
        for (int j = 0; j < WIN; ++j)
            xv[j] = rowp[(size_t)j * NBC + bc];
    } else {
        #pragma unroll
        for (int j = 0; j < WIN; ++j) {
            const int tg = tstart + j;
            xv[j] = ((unsigned)tg < (unsigned)T) ? x[(size_t)tg * NBC + bc] : 0.0f;
        }
    }

    // Fence: no FMA may be hoisted above, no load may be sunk below.
    // Forces all 62 loads to issue back-to-back (62 outstanding VMEM ops/wave),
    // keeping the full window live in VGPRs instead of a serialized load->use chain.
    __builtin_amdgcn_sched_barrier(0);

    // ---- 31 x 32 FMAs, every index compile-time ----
    float acc[TT];
    #pragma unroll
    for (int i = 0; i < TT; ++i) acc[i] = 0.0f;
    all_taps(acc, xv, w, std::make_integer_sequence<int, K>{});

    // ---- epilogue: bias + coalesced nontemporal stores (don't pollute L2) ----
    const float bb = bias[c];
    float* op = out + (size_t)t0 * NBC + bc;
    #pragma unroll
    for (int i = 0; i < TT; ++i)
        __builtin_nontemporal_store(acc[i] + bb, &op[(size_t)i * NBC]);
}

extern "C" void kernel_launch(void* const* d_in, const int* in_sizes, int n_in,
                              void* d_out, int out_size, void* d_ws, size_t ws_size,
                              hipStream_t stream) {
    const float* x    = (const float*)d_in[0];
    const float* wgt  = (const float*)d_in[1];
    const float* bias = (const float*)d_in[2];
    float* out        = (float*)d_out;

    dim3 grid(NBC / BLOCK, T / TT);   // (32, 64) = 2048 blocks, no barriers anywhere
    lconv_tbc_kernel<<<grid, dim3(BLOCK), 0, stream>>>(x, wgt, bias, out);
}